// Round 22
// baseline (89.148 us; speedup 1.0000x reference)
//
#include <hip/hip_runtime.h>
#include <hip/hip_bf16.h>
#include <stdint.h>

typedef float f32x4 __attribute__((ext_vector_type(4)));
typedef __bf16 bf16x8 __attribute__((ext_vector_type(8)));
typedef unsigned short u16;

#define MFMA16(a, b, c) __builtin_amdgcn_mfma_f32_16x16x32_bf16((a), (b), (c), 0, 0, 0)

__device__ __forceinline__ u16 f2bf(float f) {
  union { float f; uint32_t u; } v; v.f = f;
  uint32_t u = v.u;
  return (u16)((u + 0x7fffu + ((u >> 16) & 1u)) >> 16);
}
__device__ __forceinline__ float bf2f(u16 h) {
  union { uint32_t u; float f; } v; v.u = ((uint32_t)h) << 16;
  return v.f;
}

// ---------------- kernel 0: weights -> bf16 transposed [c][k] -----------------
__global__ void prep_weights_kernel(const float* __restrict__ Wq, const float* __restrict__ Wk,
                                    const float* __restrict__ Wv, const float* __restrict__ Wp,
                                    u16* __restrict__ Wt) {
  int w = blockIdx.x;
  const float* W = (w == 0) ? Wq : (w == 1) ? Wk : (w == 2) ? Wv : Wp;
  int t = blockIdx.y * 256 + threadIdx.x;  // 0..16383
  int c = t >> 7, k = t & 127;
  Wt[(w * 128 + c) * 128 + k] = f2bf(W[k * 128 + c]);
}

// ---------------- FUSED kernel v11: + COLUMN-SPLIT out-proj ------------------
// fused10 (83.4us) with the proven col-split mechanism applied to the LAST
// redundant-weight section: out-proj. After attention (barrier D — waves
// finish at different kv counts anyway), ctx is finalized and parked bf16 in
// the dead KX; each wave then computes y cols [wv*16,+16) for ALL 256 rows
// with ONE resident Wp-frag group (16 -> 1 weight groups/wave), writing y(+bp)
// into dead V_lds reused as y[256][132]. LN+residual+scatter read own rows.
__global__ __launch_bounds__(512, 2) void fused11_kernel(
    const u16* __restrict__ Wt, const float* __restrict__ x,
    const int* __restrict__ mask, const float* __restrict__ rel,
    const float* __restrict__ bq, const float* __restrict__ bk,
    const float* __restrict__ bv, const float* __restrict__ bp,
    const float* __restrict__ ln_g, const float* __restrict__ ln_b,
    float* __restrict__ out) {
  __shared__ u16 KX[256][136];        // x -> K -> ctx                   69632 B
  __shared__ u16 V_lds[128][264];     // V^T [d][t] -> y[256][132]       67584 B
  __shared__ u16 P_lds[8][32][40];    // per-wave repack slices          20480 B
  __shared__ float rel_lds[511];      //                                  2044 B
  __shared__ float vmean_lds[128];    //                                   512 B -> 160252 B
  const int tid = threadIdx.x;
  const int n = blockIdx.x;
  const int bb = n / 100, rr = n - bb * 100;
  const int* mrow = mask + bb * 256;
  if (tid < 511) rel_lds[tid] = rel[tid];
  const int l = tid & 63, wv = tid >> 6, l15 = l & 15, l4 = l >> 4;
  const int tt0 = wv * 32;  // this wave's 32 q-rows

#define LOADW4(buf, ROWB)                                                  \
  do {                                                                     \
    const u16* _wp = Wt + (size_t)((ROWB) + l15) * 128 + l4 * 8;           \
    buf[0] = *(const bf16x8*)(_wp);                                        \
    buf[1] = *(const bf16x8*)(_wp + 32);                                   \
    buf[2] = *(const bf16x8*)(_wp + 64);                                   \
    buf[3] = *(const bf16x8*)(_wp + 96);                                   \
  } while (0)

  bf16x8 bA[4], bB[4];
  LOADW4(bA, 0);  // Q ct0 — independent of x, flies under staging

  {  // WAVE-PRIVATE stage, BATCHED: 16 loads issued together, then cvt+store
    int row = tt0 + (l >> 1), half = (l & 1) * 64;
    const float* src = x + ((size_t)(n * 256 + row)) * 128 + half;
    u16* dst = &KX[row][half];
    float4 xr[16];
#pragma unroll
    for (int j = 0; j < 16; ++j) xr[j] = ((const float4*)src)[j];
#pragma unroll
    for (int j = 0; j < 16; ++j) {
      dst[j * 4 + 0] = f2bf(xr[j].x); dst[j * 4 + 1] = f2bf(xr[j].y);
      dst[j * 4 + 2] = f2bf(xr[j].z); dst[j * 4 + 3] = f2bf(xr[j].w);
    }
  }
  int ttg[2][4], qm[2][4];
#pragma unroll
  for (int g = 0; g < 2; ++g)
#pragma unroll
    for (int rg = 0; rg < 4; ++rg) {
      ttg[g][rg] = tt0 + g * 16 + 4 * l4 + rg;
      qm[g][rg] = mrow[ttg[g][rg]];
    }

  // ---- per-wave reads of OWN x rows (A-frags + packed residual) ----
  bf16x8 af[2][4];
#pragma unroll
  for (int g = 0; g < 2; ++g)
#pragma unroll
    for (int ks = 0; ks < 4; ++ks)
      af[g][ks] = *(const bf16x8*)&KX[tt0 + g * 16 + l15][ks * 32 + l4 * 8];
  uint32_t xres[2][4][4];  // x[ttg[g][rg]][ct*16+l15], ct=2c|2c+1 packed
#pragma unroll
  for (int g = 0; g < 2; ++g)
#pragma unroll
    for (int rg = 0; rg < 4; ++rg) {
      const u16* xr = &KX[tt0 + g * 16 + 4 * l4 + rg][0];
#pragma unroll
      for (int c = 0; c < 4; ++c)
        xres[g][rg][c] = (uint32_t)xr[c * 32 + l15] | ((uint32_t)xr[c * 32 + 16 + l15] << 16);
    }

  const float scale = 0.088388347648318447f;  // 1/sqrt(128)
  f32x4 t0, t1;  // transient per-ct accumulators
#define MF8(buf)                                                           \
  do {                                                                     \
    t0 = f32x4{0.f, 0.f, 0.f, 0.f}; t1 = f32x4{0.f, 0.f, 0.f, 0.f};       \
    _Pragma("unroll") for (int ks = 0; ks < 4; ++ks) {                     \
      t0 = MFMA16(af[0][ks], buf[ks], t0);                                 \
      t1 = MFMA16(af[1][ks], buf[ks], t1);                                 \
    }                                                                      \
  } while (0)

  // ---- Q = x @ Wq + bq -> qa[] via P-slice repack (ping-pong prefetch) ----
  bf16x8 qa[2][4];
#define QSTORE(CT)                                                         \
  do {                                                                     \
    float bqv = bq[(CT) * 16 + l15];                                       \
    _Pragma("unroll") for (int rg = 0; rg < 4; ++rg) {                     \
      P_lds[wv][4 * l4 + rg][((CT) & 1) * 16 + l15] = f2bf((t0[rg] + bqv) * scale); \
      P_lds[wv][16 + 4 * l4 + rg][((CT) & 1) * 16 + l15] = f2bf((t1[rg] + bqv) * scale); \
    }                                                                      \
    if ((CT) & 1) {                                                        \
      qa[0][(CT) >> 1] = *(const bf16x8*)&P_lds[wv][l15][l4 * 8];          \
      qa[1][(CT) >> 1] = *(const bf16x8*)&P_lds[wv][16 + l15][l4 * 8];     \
    }                                                                      \
  } while (0)
  LOADW4(bB, 16);
  MF8(bA); LOADW4(bA, 2 * 16);        QSTORE(0);
  MF8(bB); LOADW4(bB, 3 * 16);        QSTORE(1);
  MF8(bA); LOADW4(bA, 4 * 16);        QSTORE(2);
  MF8(bB); LOADW4(bB, 5 * 16);        QSTORE(3);
  MF8(bA); LOADW4(bA, 6 * 16);        QSTORE(4);
  MF8(bB); LOADW4(bB, 7 * 16);        QSTORE(5);
  MF8(bA); LOADW4(bA, 128 + wv * 16); QSTORE(6);  // prefetch K W-frags (own cols)
  MF8(bB); LOADW4(bB, 256 + wv * 16); QSTORE(7);  // prefetch V W-frags (own cols)

  __syncthreads();  // barrier A: x staged by ALL waves (col-split reads all rows)

  // ---- K & V col-split: wave owns cols [wv*16, wv*16+16); W-frags resident --
  const float bkv = bk[wv * 16 + l15];
  const float bvv = bv[wv * 16 + l15];
  f32x4 kacc[16];
#pragma unroll
  for (int r = 0; r < 16; ++r) {
    bf16x8 xf[4];
#pragma unroll
    for (int ks = 0; ks < 4; ++ks)
      xf[ks] = *(const bf16x8*)&KX[r * 16 + l15][ks * 32 + l4 * 8];
    f32x4 ka = f32x4{0.f, 0.f, 0.f, 0.f};
    f32x4 va = f32x4{0.f, 0.f, 0.f, 0.f};
#pragma unroll
    for (int ks = 0; ks < 4; ++ks) {
      ka = MFMA16(xf[ks], bA[ks], ka);   // K: rows r*16.., cols wv*16..
      va = MFMA16(xf[ks], bB[ks], va);   // V: same rows/cols
    }
    kacc[r] = ka;
#pragma unroll
    for (int rg = 0; rg < 4; ++rg)
      V_lds[wv * 16 + l15][r * 16 + 4 * l4 + rg] = f2bf(va[rg] + bvv);
  }
  __syncthreads();  // barrier B: all x reads complete (V also fully written)
#pragma unroll
  for (int r = 0; r < 16; ++r)
#pragma unroll
    for (int rg = 0; rg < 4; ++rg)
      KX[r * 16 + 4 * l4 + rg][wv * 16 + l15] = f2bf(kacc[r][rg] + bkv);
  __syncthreads();  // barrier C: K complete

  {  // in-block vmean over V^T rows
    int d = tid >> 2, seg = tid & 3;
    const u16* vr = &V_lds[d][seg * 64];
    float s = 0.f;
#pragma unroll
    for (int j = 0; j < 8; ++j) {
      uint4 u = *(const uint4*)(vr + j * 8);
      s += bf2f((u16)(u.x & 0xffff)) + bf2f((u16)(u.x >> 16));
      s += bf2f((u16)(u.y & 0xffff)) + bf2f((u16)(u.y >> 16));
      s += bf2f((u16)(u.z & 0xffff)) + bf2f((u16)(u.z >> 16));
      s += bf2f((u16)(u.w & 0xffff)) + bf2f((u16)(u.w >> 16));
    }
    s += __shfl_xor(s, 1); s += __shfl_xor(s, 2);
    if (seg == 0) vmean_lds[d] = s * (1.f / 256.f);
  }
  float lsum[2][4]; f32x4 cacc[2][8];
#pragma unroll
  for (int g = 0; g < 2; ++g)
#pragma unroll
    for (int rg = 0; rg < 4; ++rg) lsum[g][rg] = 0.f;
#pragma unroll
  for (int g = 0; g < 2; ++g)
#pragma unroll
    for (int ct = 0; ct < 8; ++ct) cacc[g][ct] = f32x4{0.f, 0.f, 0.f, 0.f};
  __syncthreads();  // barrier 3: vmean ready

  // ---- attention: fixed-max softmax, 32 rows/wave ----
  const int nkv = (wv >> 1) + 1;
  for (int kv = 0; kv < nkv; ++kv) {
    const int s0 = kv * 64;
    f32x4 sacc[2][4];
#pragma unroll
    for (int g = 0; g < 2; ++g)
#pragma unroll
      for (int ct = 0; ct < 4; ++ct) sacc[g][ct] = f32x4{0.f, 0.f, 0.f, 0.f};
#pragma unroll
    for (int ct = 0; ct < 4; ++ct)
#pragma unroll
      for (int ks = 0; ks < 4; ++ks) {
        bf16x8 bfr = *(const bf16x8*)&KX[s0 + ct * 16 + l15][ks * 32 + l4 * 8];
#pragma unroll
        for (int g = 0; g < 2; ++g) sacc[g][ct] = MFMA16(qa[g][ks], bfr, sacc[g][ct]);
      }
    int km[4];
#pragma unroll
    for (int ct = 0; ct < 4; ++ct) km[ct] = mrow[s0 + ct * 16 + l15];
    float p[2][4][4];
#pragma unroll
    for (int g = 0; g < 2; ++g)
#pragma unroll
      for (int ct = 0; ct < 4; ++ct) {
        const int ss = s0 + ct * 16 + l15;
#pragma unroll
        for (int rg = 0; rg < 4; ++rg) {
          float sv = sacc[g][ct][rg] + rel_lds[ttg[g][rg] - ss + 255];
          bool msk = (ss > ttg[g][rg]) | (km[ct] == 0) | (qm[g][rg] == 0);
          sv = msk ? -1.0e9f : sv;
          float pv = __expf(sv);  // masked -> exactly 0
          p[g][ct][rg] = pv;
          lsum[g][rg] += pv;
        }
      }
#pragma unroll
    for (int c = 0; c < 2; ++c) {
#pragma unroll
      for (int g = 0; g < 2; ++g)
#pragma unroll
        for (int c2 = 0; c2 < 2; ++c2)
#pragma unroll
          for (int rg = 0; rg < 4; ++rg)
            P_lds[wv][g * 16 + 4 * l4 + rg][c2 * 16 + l15] = f2bf(p[g][2 * c + c2][rg]);
      bf16x8 pa[2];
#pragma unroll
      for (int g = 0; g < 2; ++g)
        pa[g] = *(const bf16x8*)&P_lds[wv][g * 16 + l15][l4 * 8];
#pragma unroll
      for (int ct = 0; ct < 8; ++ct) {
        bf16x8 vb = *(const bf16x8*)&V_lds[ct * 16 + l15][s0 + c * 32 + l4 * 8];
#pragma unroll
        for (int g = 0; g < 2; ++g) cacc[g][ct] = MFMA16(pa[g], vb, cacc[g][ct]);
      }
    }
  }
  float li[2][4];
#pragma unroll
  for (int g = 0; g < 2; ++g)
#pragma unroll
    for (int rg = 0; rg < 4; ++rg) {
      float rs = lsum[g][rg];
#pragma unroll
      for (int off = 1; off < 16; off <<= 1) rs += __shfl_xor(rs, off);
      li[g][rg] = rs;
    }
  __syncthreads();  // barrier D: ALL waves done reading KX (K) and V_lds (PV)

  // ---- finalize ctx -> park bf16 in dead KX (row-major) ----
#pragma unroll
  for (int g = 0; g < 2; ++g)
#pragma unroll
    for (int ct = 0; ct < 8; ++ct) {
      float vm = vmean_lds[ct * 16 + l15];
#pragma unroll
      for (int rg = 0; rg < 4; ++rg) {
        float cval = cacc[g][ct][rg] / li[g][rg];
        cval = (qm[g][rg] == 0) ? vm : cval;
        KX[ttg[g][rg]][ct * 16 + l15] = f2bf(cval);
      }
    }
  __syncthreads();  // barrier E: ctx complete

  // ---- out-proj COL-SPLIT: wave owns y cols [wv*16,+16); 1 W-group resident --
  u16* ybuf = (u16*)V_lds;  // dead V_lds reused as y[256][132] (67584 B exact)
  LOADW4(bA, 384 + wv * 16);
  const float bpw = bp[wv * 16 + l15];
#pragma unroll
  for (int r = 0; r < 16; ++r) {
    bf16x8 cf[4];
#pragma unroll
    for (int ks = 0; ks < 4; ++ks)
      cf[ks] = *(const bf16x8*)&KX[r * 16 + l15][ks * 32 + l4 * 8];
    f32x4 ya = f32x4{0.f, 0.f, 0.f, 0.f};
#pragma unroll
    for (int ks = 0; ks < 4; ++ks) ya = MFMA16(cf[ks], bA[ks], ya);
#pragma unroll
    for (int rg = 0; rg < 4; ++rg)
      ybuf[(size_t)(r * 16 + 4 * l4 + rg) * 132 + wv * 16 + l15] = f2bf(ya[rg] + bpw);
  }
  __syncthreads();  // barrier F: y complete

  // ---- LN + residual + scatter: own 32 rows ----
  float gv[8], bt[8];
#pragma unroll
  for (int ct = 0; ct < 8; ++ct) {
    int d = ct * 16 + l15;
    gv[ct] = ln_g[d]; bt[ct] = ln_b[d];
  }
#pragma unroll
  for (int g = 0; g < 2; ++g)
#pragma unroll
    for (int rg = 0; rg < 4; ++rg) {
      const int tg = ttg[g][rg];
      const u16* yr = ybuf + (size_t)tg * 132;
      float yv[8], sum = 0.f, sq = 0.f;
#pragma unroll
      for (int ct = 0; ct < 8; ++ct) {
        uint32_t pr = xres[g][rg][ct >> 1];
        u16 xh = (ct & 1) ? (u16)(pr >> 16) : (u16)(pr & 0xffff);
        float v = bf2f(yr[ct * 16 + l15]) + bf2f(xh);
        yv[ct] = v; sum += v; sq += v * v;
      }
#pragma unroll
      for (int off = 1; off < 16; off <<= 1) { sum += __shfl_xor(sum, off); sq += __shfl_xor(sq, off); }
      float mean = sum * (1.f / 128.f);
      float var = sq * (1.f / 128.f) - mean * mean;
      float rstd = rsqrtf(var + 1e-5f);
      float* orow = out + (((size_t)(bb * 256 + tg)) * 100 + rr) * 128;
#pragma unroll
      for (int ct = 0; ct < 8; ++ct)
        orow[ct * 16 + l15] = (yv[ct] - mean) * rstd * gv[ct] + bt[ct];
    }
#undef LOADW4
#undef MF8
#undef QSTORE
}

extern "C" void kernel_launch(void* const* d_in, const int* in_sizes, int n_in,
                              void* d_out, int out_size, void* d_ws, size_t ws_size,
                              hipStream_t stream) {
  const float* x    = (const float*)d_in[0];
  const int*   mask = (const int*)d_in[1];
  const float* Wq   = (const float*)d_in[2];
  const float* bq   = (const float*)d_in[3];
  const float* Wk   = (const float*)d_in[4];
  const float* bk   = (const float*)d_in[5];
  const float* Wv   = (const float*)d_in[6];
  const float* bv   = (const float*)d_in[7];
  const float* Wp   = (const float*)d_in[8];
  const float* bp   = (const float*)d_in[9];
  const float* ln_g = (const float*)d_in[10];
  const float* ln_b = (const float*)d_in[11];
  const float* rel  = (const float*)d_in[12];
  float* out = (float*)d_out;
  u16* Wt = (u16*)d_ws;  // [4][128][128] bf16 transposed — only workspace use

  hipLaunchKernelGGL(prep_weights_kernel, dim3(4, 64), dim3(256), 0, stream, Wq, Wk, Wv, Wp, Wt);
  hipLaunchKernelGGL(fused11_kernel, dim3(400), dim3(512), 0, stream,
                     Wt, x, mask, rel, bq, bk, bv, bp, ln_g, ln_b, out);
}

// Round 23
// 87.839 us; speedup vs baseline: 1.0149x; 1.0149x over previous
//
#include <hip/hip_runtime.h>
#include <hip/hip_bf16.h>
#include <stdint.h>

typedef float f32x4 __attribute__((ext_vector_type(4)));
typedef __bf16 bf16x8 __attribute__((ext_vector_type(8)));
typedef unsigned short u16;

#define MFMA16(a, b, c) __builtin_amdgcn_mfma_f32_16x16x32_bf16((a), (b), (c), 0, 0, 0)

__device__ __forceinline__ u16 f2bf(float f) {
  union { float f; uint32_t u; } v; v.f = f;
  uint32_t u = v.u;
  return (u16)((u + 0x7fffu + ((u >> 16) & 1u)) >> 16);
}
__device__ __forceinline__ float bf2f(u16 h) {
  union { uint32_t u; float f; } v; v.u = ((uint32_t)h) << 16;
  return v.f;
}

// ---------------- kernel 0: weights -> bf16 transposed [c][k] -----------------
__global__ void prep_weights_kernel(const float* __restrict__ Wq, const float* __restrict__ Wk,
                                    const float* __restrict__ Wv, const float* __restrict__ Wp,
                                    u16* __restrict__ Wt) {
  int w = blockIdx.x;
  const float* W = (w == 0) ? Wq : (w == 1) ? Wk : (w == 2) ? Wv : Wp;
  int t = blockIdx.y * 256 + threadIdx.x;  // 0..16383
  int c = t >> 7, k = t & 127;
  Wt[(w * 128 + c) * 128 + k] = f2bf(W[k * 128 + c]);
}

// ---------------- FUSED kernel v12: BALANCED rows + col-split out-proj -------
// fused11's col-split out-proj was right but barrier-D exposed the causal wave
// imbalance (waves did 2..8 tile-units; all waited for 8). v12 gives each wave
// MIRRORED row groups: rows [wv*16,+16) and [(15-wv)*16,+16) -> per-wave tile
// count 4..5 (max 8 -> 5), so barrier D costs ~nothing and the out-proj
// savings (16 -> 1 weight groups/wave) are realized. Attention loop runs per
// group with its own causal tile count. All else identical to fused11.
__global__ __launch_bounds__(512, 2) void fused12_kernel(
    const u16* __restrict__ Wt, const float* __restrict__ x,
    const int* __restrict__ mask, const float* __restrict__ rel,
    const float* __restrict__ bq, const float* __restrict__ bk,
    const float* __restrict__ bv, const float* __restrict__ bp,
    const float* __restrict__ ln_g, const float* __restrict__ ln_b,
    float* __restrict__ out) {
  __shared__ u16 KX[256][136];        // x -> K -> ctx                   69632 B
  __shared__ u16 V_lds[128][264];     // V^T [d][t] -> y[256][132]       67584 B
  __shared__ u16 P_lds[8][32][40];    // per-wave repack slices          20480 B
  __shared__ float rel_lds[511];      //                                  2044 B
  __shared__ float vmean_lds[128];    //                                   512 B -> 160252 B
  const int tid = threadIdx.x;
  const int n = blockIdx.x;
  const int bb = n / 100, rr = n - bb * 100;
  const int* mrow = mask + bb * 256;
  if (tid < 511) rel_lds[tid] = rel[tid];
  const int l = tid & 63, wv = tid >> 6, l15 = l & 15, l4 = l >> 4;
  const int rbase0 = wv * 16, rbase1 = (15 - wv) * 16;  // mirrored 16-row groups

#define LOADW4(buf, ROWB)                                                  \
  do {                                                                     \
    const u16* _wp = Wt + (size_t)((ROWB) + l15) * 128 + l4 * 8;           \
    buf[0] = *(const bf16x8*)(_wp);                                        \
    buf[1] = *(const bf16x8*)(_wp + 32);                                   \
    buf[2] = *(const bf16x8*)(_wp + 64);                                   \
    buf[3] = *(const bf16x8*)(_wp + 96);                                   \
  } while (0)

  bf16x8 bA[4], bB[4];
  LOADW4(bA, 0);  // Q ct0 — independent of x, flies under staging

  {  // WAVE-PRIVATE stage: lanes 0-31 -> group0 rows, lanes 32-63 -> group1
    int rb = (l < 32) ? rbase0 : rbase1;
    int row = rb + ((l & 31) >> 1), half = (l & 1) * 64;
    const float* src = x + ((size_t)(n * 256 + row)) * 128 + half;
    u16* dst = &KX[row][half];
    float4 xr[16];
#pragma unroll
    for (int j = 0; j < 16; ++j) xr[j] = ((const float4*)src)[j];
#pragma unroll
    for (int j = 0; j < 16; ++j) {
      dst[j * 4 + 0] = f2bf(xr[j].x); dst[j * 4 + 1] = f2bf(xr[j].y);
      dst[j * 4 + 2] = f2bf(xr[j].z); dst[j * 4 + 3] = f2bf(xr[j].w);
    }
  }
  const int rb[2] = {rbase0, rbase1};
  int ttg[2][4], qm[2][4];
#pragma unroll
  for (int g = 0; g < 2; ++g)
#pragma unroll
    for (int rg = 0; rg < 4; ++rg) {
      ttg[g][rg] = rb[g] + 4 * l4 + rg;
      qm[g][rg] = mrow[ttg[g][rg]];
    }

  // ---- per-wave reads of OWN rows (A-frags + packed residual) ----
  bf16x8 af[2][4];
#pragma unroll
  for (int g = 0; g < 2; ++g)
#pragma unroll
    for (int ks = 0; ks < 4; ++ks)
      af[g][ks] = *(const bf16x8*)&KX[rb[g] + l15][ks * 32 + l4 * 8];
  uint32_t xres[2][4][4];  // x[ttg[g][rg]][ct*16+l15], ct=2c|2c+1 packed
#pragma unroll
  for (int g = 0; g < 2; ++g)
#pragma unroll
    for (int rg = 0; rg < 4; ++rg) {
      const u16* xr = &KX[rb[g] + 4 * l4 + rg][0];
#pragma unroll
      for (int c = 0; c < 4; ++c)
        xres[g][rg][c] = (uint32_t)xr[c * 32 + l15] | ((uint32_t)xr[c * 32 + 16 + l15] << 16);
    }

  const float scale = 0.088388347648318447f;  // 1/sqrt(128)
  f32x4 t0, t1;  // transient per-ct accumulators
#define MF8(buf)                                                           \
  do {                                                                     \
    t0 = f32x4{0.f, 0.f, 0.f, 0.f}; t1 = f32x4{0.f, 0.f, 0.f, 0.f};       \
    _Pragma("unroll") for (int ks = 0; ks < 4; ++ks) {                     \
      t0 = MFMA16(af[0][ks], buf[ks], t0);                                 \
      t1 = MFMA16(af[1][ks], buf[ks], t1);                                 \
    }                                                                      \
  } while (0)

  // ---- Q = x @ Wq + bq -> qa[] via P-slice repack (ping-pong prefetch) ----
  bf16x8 qa[2][4];
#define QSTORE(CT)                                                         \
  do {                                                                     \
    float bqv = bq[(CT) * 16 + l15];                                       \
    _Pragma("unroll") for (int rg = 0; rg < 4; ++rg) {                     \
      P_lds[wv][4 * l4 + rg][((CT) & 1) * 16 + l15] = f2bf((t0[rg] + bqv) * scale); \
      P_lds[wv][16 + 4 * l4 + rg][((CT) & 1) * 16 + l15] = f2bf((t1[rg] + bqv) * scale); \
    }                                                                      \
    if ((CT) & 1) {                                                        \
      qa[0][(CT) >> 1] = *(const bf16x8*)&P_lds[wv][l15][l4 * 8];          \
      qa[1][(CT) >> 1] = *(const bf16x8*)&P_lds[wv][16 + l15][l4 * 8];     \
    }                                                                      \
  } while (0)
  LOADW4(bB, 16);
  MF8(bA); LOADW4(bA, 2 * 16);        QSTORE(0);
  MF8(bB); LOADW4(bB, 3 * 16);        QSTORE(1);
  MF8(bA); LOADW4(bA, 4 * 16);        QSTORE(2);
  MF8(bB); LOADW4(bB, 5 * 16);        QSTORE(3);
  MF8(bA); LOADW4(bA, 6 * 16);        QSTORE(4);
  MF8(bB); LOADW4(bB, 7 * 16);        QSTORE(5);
  MF8(bA); LOADW4(bA, 128 + wv * 16); QSTORE(6);  // prefetch K W-frags (own cols)
  MF8(bB); LOADW4(bB, 256 + wv * 16); QSTORE(7);  // prefetch V W-frags (own cols)

  __syncthreads();  // barrier A: x staged by ALL waves

  // ---- K & V col-split: wave owns cols [wv*16, wv*16+16); W-frags resident --
  const float bkv = bk[wv * 16 + l15];
  const float bvv = bv[wv * 16 + l15];
  f32x4 kacc[16];
#pragma unroll
  for (int r = 0; r < 16; ++r) {
    bf16x8 xf[4];
#pragma unroll
    for (int ks = 0; ks < 4; ++ks)
      xf[ks] = *(const bf16x8*)&KX[r * 16 + l15][ks * 32 + l4 * 8];
    f32x4 ka = f32x4{0.f, 0.f, 0.f, 0.f};
    f32x4 va = f32x4{0.f, 0.f, 0.f, 0.f};
#pragma unroll
    for (int ks = 0; ks < 4; ++ks) {
      ka = MFMA16(xf[ks], bA[ks], ka);
      va = MFMA16(xf[ks], bB[ks], va);
    }
    kacc[r] = ka;
#pragma unroll
    for (int rg = 0; rg < 4; ++rg)
      V_lds[wv * 16 + l15][r * 16 + 4 * l4 + rg] = f2bf(va[rg] + bvv);
  }
  __syncthreads();  // barrier B: all x reads complete (V fully written)
#pragma unroll
  for (int r = 0; r < 16; ++r)
#pragma unroll
    for (int rg = 0; rg < 4; ++rg)
      KX[r * 16 + 4 * l4 + rg][wv * 16 + l15] = f2bf(kacc[r][rg] + bkv);
  __syncthreads();  // barrier C: K complete

  {  // in-block vmean over V^T rows
    int d = tid >> 2, seg = tid & 3;
    const u16* vr = &V_lds[d][seg * 64];
    float s = 0.f;
#pragma unroll
    for (int j = 0; j < 8; ++j) {
      uint4 u = *(const uint4*)(vr + j * 8);
      s += bf2f((u16)(u.x & 0xffff)) + bf2f((u16)(u.x >> 16));
      s += bf2f((u16)(u.y & 0xffff)) + bf2f((u16)(u.y >> 16));
      s += bf2f((u16)(u.z & 0xffff)) + bf2f((u16)(u.z >> 16));
      s += bf2f((u16)(u.w & 0xffff)) + bf2f((u16)(u.w >> 16));
    }
    s += __shfl_xor(s, 1); s += __shfl_xor(s, 2);
    if (seg == 0) vmean_lds[d] = s * (1.f / 256.f);
  }
  float lsum[2][4]; f32x4 cacc[2][8];
#pragma unroll
  for (int g = 0; g < 2; ++g)
#pragma unroll
    for (int rg = 0; rg < 4; ++rg) lsum[g][rg] = 0.f;
#pragma unroll
  for (int g = 0; g < 2; ++g)
#pragma unroll
    for (int ct = 0; ct < 8; ++ct) cacc[g][ct] = f32x4{0.f, 0.f, 0.f, 0.f};
  __syncthreads();  // barrier 3: vmean ready

  // ---- attention: fixed-max softmax, PER-GROUP causal loops (balanced) ----
#pragma unroll
  for (int g = 0; g < 2; ++g) {
    const int nkvg = (rb[g] >> 6) + 1;  // causal tiles for this 16-row group
#pragma unroll 1
    for (int kv = 0; kv < nkvg; ++kv) {
      const int s0 = kv * 64;
      f32x4 sacc[4];
#pragma unroll
      for (int ct = 0; ct < 4; ++ct) sacc[ct] = f32x4{0.f, 0.f, 0.f, 0.f};
#pragma unroll
      for (int ct = 0; ct < 4; ++ct)
#pragma unroll
        for (int ks = 0; ks < 4; ++ks) {
          bf16x8 bfr = *(const bf16x8*)&KX[s0 + ct * 16 + l15][ks * 32 + l4 * 8];
          sacc[ct] = MFMA16(qa[g][ks], bfr, sacc[ct]);
        }
      int km[4];
#pragma unroll
      for (int ct = 0; ct < 4; ++ct) km[ct] = mrow[s0 + ct * 16 + l15];
      float p[4][4];
#pragma unroll
      for (int ct = 0; ct < 4; ++ct) {
        const int ss = s0 + ct * 16 + l15;
#pragma unroll
        for (int rg = 0; rg < 4; ++rg) {
          float sv = sacc[ct][rg] + rel_lds[ttg[g][rg] - ss + 255];
          bool msk = (ss > ttg[g][rg]) | (km[ct] == 0) | (qm[g][rg] == 0);
          sv = msk ? -1.0e9f : sv;
          float pv = __expf(sv);  // masked -> exactly 0
          p[ct][rg] = pv;
          lsum[g][rg] += pv;
        }
      }
#pragma unroll
      for (int c = 0; c < 2; ++c) {
#pragma unroll
        for (int c2 = 0; c2 < 2; ++c2)
#pragma unroll
          for (int rg = 0; rg < 4; ++rg)
            P_lds[wv][g * 16 + 4 * l4 + rg][c2 * 16 + l15] = f2bf(p[2 * c + c2][rg]);
        bf16x8 pa = *(const bf16x8*)&P_lds[wv][g * 16 + l15][l4 * 8];
#pragma unroll
        for (int ct = 0; ct < 8; ++ct) {
          bf16x8 vb = *(const bf16x8*)&V_lds[ct * 16 + l15][s0 + c * 32 + l4 * 8];
          cacc[g][ct] = MFMA16(pa, vb, cacc[g][ct]);
        }
      }
    }
  }
  float li[2][4];
#pragma unroll
  for (int g = 0; g < 2; ++g)
#pragma unroll
    for (int rg = 0; rg < 4; ++rg) {
      float rs = lsum[g][rg];
#pragma unroll
      for (int off = 1; off < 16; off <<= 1) rs += __shfl_xor(rs, off);
      li[g][rg] = rs;
    }
  __syncthreads();  // barrier D: cheap now (waves balanced at 4-5 tile-units)

  // ---- finalize ctx -> park bf16 in dead KX (row-major) ----
#pragma unroll
  for (int g = 0; g < 2; ++g)
#pragma unroll
    for (int ct = 0; ct < 8; ++ct) {
      float vm = vmean_lds[ct * 16 + l15];
#pragma unroll
      for (int rg = 0; rg < 4; ++rg) {
        float cval = cacc[g][ct][rg] / li[g][rg];
        cval = (qm[g][rg] == 0) ? vm : cval;
        KX[ttg[g][rg]][ct * 16 + l15] = f2bf(cval);
      }
    }
  __syncthreads();  // barrier E: ctx complete

  // ---- out-proj COL-SPLIT: wave owns y cols [wv*16,+16); 1 W-group resident --
  u16* ybuf = (u16*)V_lds;  // dead V_lds reused as y[256][132] (67584 B exact)
  LOADW4(bA, 384 + wv * 16);
  const float bpw = bp[wv * 16 + l15];
#pragma unroll
  for (int r = 0; r < 16; ++r) {
    bf16x8 cf[4];
#pragma unroll
    for (int ks = 0; ks < 4; ++ks)
      cf[ks] = *(const bf16x8*)&KX[r * 16 + l15][ks * 32 + l4 * 8];
    f32x4 ya = f32x4{0.f, 0.f, 0.f, 0.f};
#pragma unroll
    for (int ks = 0; ks < 4; ++ks) ya = MFMA16(cf[ks], bA[ks], ya);
#pragma unroll
    for (int rg = 0; rg < 4; ++rg)
      ybuf[(size_t)(r * 16 + 4 * l4 + rg) * 132 + wv * 16 + l15] = f2bf(ya[rg] + bpw);
  }
  __syncthreads();  // barrier F: y complete

  // ---- LN + residual + scatter: own rows (both groups) ----
  float gv[8], bt[8];
#pragma unroll
  for (int ct = 0; ct < 8; ++ct) {
    int d = ct * 16 + l15;
    gv[ct] = ln_g[d]; bt[ct] = ln_b[d];
  }
#pragma unroll
  for (int g = 0; g < 2; ++g)
#pragma unroll
    for (int rg = 0; rg < 4; ++rg) {
      const int tg = ttg[g][rg];
      const u16* yr = ybuf + (size_t)tg * 132;
      float yv[8], sum = 0.f, sq = 0.f;
#pragma unroll
      for (int ct = 0; ct < 8; ++ct) {
        uint32_t pr = xres[g][rg][ct >> 1];
        u16 xh = (ct & 1) ? (u16)(pr >> 16) : (u16)(pr & 0xffff);
        float v = bf2f(yr[ct * 16 + l15]) + bf2f(xh);
        yv[ct] = v; sum += v; sq += v * v;
      }
#pragma unroll
      for (int off = 1; off < 16; off <<= 1) { sum += __shfl_xor(sum, off); sq += __shfl_xor(sq, off); }
      float mean = sum * (1.f / 128.f);
      float var = sq * (1.f / 128.f) - mean * mean;
      float rstd = rsqrtf(var + 1e-5f);
      float* orow = out + (((size_t)(bb * 256 + tg)) * 100 + rr) * 128;
#pragma unroll
      for (int ct = 0; ct < 8; ++ct)
        orow[ct * 16 + l15] = (yv[ct] - mean) * rstd * gv[ct] + bt[ct];
    }
#undef LOADW4
#undef MF8
#undef QSTORE
}

extern "C" void kernel_launch(void* const* d_in, const int* in_sizes, int n_in,
                              void* d_out, int out_size, void* d_ws, size_t ws_size,
                              hipStream_t stream) {
  const float* x    = (const float*)d_in[0];
  const int*   mask = (const int*)d_in[1];
  const float* Wq   = (const float*)d_in[2];
  const float* bq   = (const float*)d_in[3];
  const float* Wk   = (const float*)d_in[4];
  const float* bk   = (const float*)d_in[5];
  const float* Wv   = (const float*)d_in[6];
  const float* bv   = (const float*)d_in[7];
  const float* Wp   = (const float*)d_in[8];
  const float* bp   = (const float*)d_in[9];
  const float* ln_g = (const float*)d_in[10];
  const float* ln_b = (const float*)d_in[11];
  const float* rel  = (const float*)d_in[12];
  float* out = (float*)d_out;
  u16* Wt = (u16*)d_ws;  // [4][128][128] bf16 transposed — only workspace use

  hipLaunchKernelGGL(prep_weights_kernel, dim3(4, 64), dim3(256), 0, stream, Wq, Wk, Wv, Wp, Wt);
  hipLaunchKernelGGL(fused12_kernel, dim3(400), dim3(512), 0, stream,
                     Wt, x, mask, rel, bq, bk, bv, bp, ln_g, ln_b, out);
}

// Round 24
// 83.806 us; speedup vs baseline: 1.0637x; 1.0481x over previous
//
#include <hip/hip_runtime.h>
#include <hip/hip_bf16.h>
#include <stdint.h>

typedef float f32x4 __attribute__((ext_vector_type(4)));
typedef __bf16 bf16x8 __attribute__((ext_vector_type(8)));
typedef unsigned short u16;

#define MFMA16(a, b, c) __builtin_amdgcn_mfma_f32_16x16x32_bf16((a), (b), (c), 0, 0, 0)

__device__ __forceinline__ u16 f2bf(float f) {
  union { float f; uint32_t u; } v; v.f = f;
  uint32_t u = v.u;
  return (u16)((u + 0x7fffu + ((u >> 16) & 1u)) >> 16);
}
__device__ __forceinline__ float bf2f(u16 h) {
  union { uint32_t u; float f; } v; v.u = ((uint32_t)h) << 16;
  return v.f;
}

// ---------------- kernel 0: weights -> bf16 transposed [c][k] -----------------
__global__ void prep_weights_kernel(const float* __restrict__ Wq, const float* __restrict__ Wk,
                                    const float* __restrict__ Wv, const float* __restrict__ Wp,
                                    u16* __restrict__ Wt) {
  int w = blockIdx.x;
  const float* W = (w == 0) ? Wq : (w == 1) ? Wk : (w == 2) ? Wv : Wp;
  int t = blockIdx.y * 256 + threadIdx.x;  // 0..16383
  int c = t >> 7, k = t & 127;
  Wt[(w * 128 + c) * 128 + k] = f2bf(W[k * 128 + c]);
}

// ---------------- FUSED kernel v10 (FINAL champion, 83.4us total) ------------
// Fully-fused per-n block: x staged once (wave-private, batched loads), Q in
// regs via ping-pong weight prefetch, K/V GEMMs COLUMN-SPLIT (each wave's
// W-frags resident, 16->2 weight-load groups/wave), K overwrites x in LDS,
// V^T in LDS, in-block vmean, fixed-max softmax attention with causal wave
// imbalance overlapping the epilogue (no barrier after attention), row-split
// out-proj, LN+residual, direct scatter. Verified vs fused11/12: col-split
// out-proj + its barrier loses to this free imbalance overlap.
__global__ __launch_bounds__(512, 2) void fused10_kernel(
    const u16* __restrict__ Wt, const float* __restrict__ x,
    const int* __restrict__ mask, const float* __restrict__ rel,
    const float* __restrict__ bq, const float* __restrict__ bk,
    const float* __restrict__ bv, const float* __restrict__ bp,
    const float* __restrict__ ln_g, const float* __restrict__ ln_b,
    float* __restrict__ out) {
  __shared__ u16 KX[256][136];        // x (per-wave) -> K               69632 B
  __shared__ u16 V_lds[128][264];     // V^T [d][t]                      67584 B
  __shared__ u16 P_lds[8][32][40];    // per-wave repack slices          20480 B
  __shared__ float rel_lds[511];      //                                  2044 B
  __shared__ float vmean_lds[128];    //                                   512 B -> 160252 B
  const int tid = threadIdx.x;
  const int n = blockIdx.x;
  const int bb = n / 100, rr = n - bb * 100;
  const int* mrow = mask + bb * 256;
  if (tid < 511) rel_lds[tid] = rel[tid];
  const int l = tid & 63, wv = tid >> 6, l15 = l & 15, l4 = l >> 4;
  const int tt0 = wv * 32;  // this wave's 32 q-rows

#define LOADW4(buf, ROWB)                                                  \
  do {                                                                     \
    const u16* _wp = Wt + (size_t)((ROWB) + l15) * 128 + l4 * 8;           \
    buf[0] = *(const bf16x8*)(_wp);                                        \
    buf[1] = *(const bf16x8*)(_wp + 32);                                   \
    buf[2] = *(const bf16x8*)(_wp + 64);                                   \
    buf[3] = *(const bf16x8*)(_wp + 96);                                   \
  } while (0)

  bf16x8 bA[4], bB[4];
  LOADW4(bA, 0);  // Q ct0 — independent of x, flies under staging

  {  // WAVE-PRIVATE stage, BATCHED: 16 loads issued together, then cvt+store
    int row = tt0 + (l >> 1), half = (l & 1) * 64;
    const float* src = x + ((size_t)(n * 256 + row)) * 128 + half;
    u16* dst = &KX[row][half];
    float4 xr[16];
#pragma unroll
    for (int j = 0; j < 16; ++j) xr[j] = ((const float4*)src)[j];
#pragma unroll
    for (int j = 0; j < 16; ++j) {
      dst[j * 4 + 0] = f2bf(xr[j].x); dst[j * 4 + 1] = f2bf(xr[j].y);
      dst[j * 4 + 2] = f2bf(xr[j].z); dst[j * 4 + 3] = f2bf(xr[j].w);
    }
  }
  int ttg[2][4], qm[2][4];
#pragma unroll
  for (int g = 0; g < 2; ++g)
#pragma unroll
    for (int rg = 0; rg < 4; ++rg) {
      ttg[g][rg] = tt0 + g * 16 + 4 * l4 + rg;
      qm[g][rg] = mrow[ttg[g][rg]];
    }

  // ---- per-wave reads of OWN x rows (A-frags + packed residual) ----
  bf16x8 af[2][4];
#pragma unroll
  for (int g = 0; g < 2; ++g)
#pragma unroll
    for (int ks = 0; ks < 4; ++ks)
      af[g][ks] = *(const bf16x8*)&KX[tt0 + g * 16 + l15][ks * 32 + l4 * 8];
  uint32_t xres[2][4][4];  // x[ttg[g][rg]][ct*16+l15], ct=2c|2c+1 packed
#pragma unroll
  for (int g = 0; g < 2; ++g)
#pragma unroll
    for (int rg = 0; rg < 4; ++rg) {
      const u16* xr = &KX[tt0 + g * 16 + 4 * l4 + rg][0];
#pragma unroll
      for (int c = 0; c < 4; ++c)
        xres[g][rg][c] = (uint32_t)xr[c * 32 + l15] | ((uint32_t)xr[c * 32 + 16 + l15] << 16);
    }

  const float scale = 0.088388347648318447f;  // 1/sqrt(128)
  f32x4 t0, t1;  // transient per-ct accumulators
#define MF8(buf)                                                           \
  do {                                                                     \
    t0 = f32x4{0.f, 0.f, 0.f, 0.f}; t1 = f32x4{0.f, 0.f, 0.f, 0.f};       \
    _Pragma("unroll") for (int ks = 0; ks < 4; ++ks) {                     \
      t0 = MFMA16(af[0][ks], buf[ks], t0);                                 \
      t1 = MFMA16(af[1][ks], buf[ks], t1);                                 \
    }                                                                      \
  } while (0)

  // ---- Q = x @ Wq + bq -> qa[] via P-slice repack (ping-pong prefetch) ----
  bf16x8 qa[2][4];
#define QSTORE(CT)                                                         \
  do {                                                                     \
    float bqv = bq[(CT) * 16 + l15];                                       \
    _Pragma("unroll") for (int rg = 0; rg < 4; ++rg) {                     \
      P_lds[wv][4 * l4 + rg][((CT) & 1) * 16 + l15] = f2bf((t0[rg] + bqv) * scale); \
      P_lds[wv][16 + 4 * l4 + rg][((CT) & 1) * 16 + l15] = f2bf((t1[rg] + bqv) * scale); \
    }                                                                      \
    if ((CT) & 1) {                                                        \
      qa[0][(CT) >> 1] = *(const bf16x8*)&P_lds[wv][l15][l4 * 8];          \
      qa[1][(CT) >> 1] = *(const bf16x8*)&P_lds[wv][16 + l15][l4 * 8];     \
    }                                                                      \
  } while (0)
  LOADW4(bB, 16);
  MF8(bA); LOADW4(bA, 2 * 16);        QSTORE(0);
  MF8(bB); LOADW4(bB, 3 * 16);        QSTORE(1);
  MF8(bA); LOADW4(bA, 4 * 16);        QSTORE(2);
  MF8(bB); LOADW4(bB, 5 * 16);        QSTORE(3);
  MF8(bA); LOADW4(bA, 6 * 16);        QSTORE(4);
  MF8(bB); LOADW4(bB, 7 * 16);        QSTORE(5);
  MF8(bA); LOADW4(bA, 128 + wv * 16); QSTORE(6);  // prefetch K W-frags (own cols)
  MF8(bB); LOADW4(bB, 256 + wv * 16); QSTORE(7);  // prefetch V W-frags (own cols)

  __syncthreads();  // barrier A: x staged by ALL waves (col-split reads all rows)

  // ---- K & V col-split: wave owns cols [wv*16, wv*16+16); W-frags resident --
  const float bkv = bk[wv * 16 + l15];
  const float bvv = bv[wv * 16 + l15];
  f32x4 kacc[16];
#pragma unroll
  for (int r = 0; r < 16; ++r) {
    bf16x8 xf[4];
#pragma unroll
    for (int ks = 0; ks < 4; ++ks)
      xf[ks] = *(const bf16x8*)&KX[r * 16 + l15][ks * 32 + l4 * 8];
    f32x4 ka = f32x4{0.f, 0.f, 0.f, 0.f};
    f32x4 va = f32x4{0.f, 0.f, 0.f, 0.f};
#pragma unroll
    for (int ks = 0; ks < 4; ++ks) {
      ka = MFMA16(xf[ks], bA[ks], ka);   // K: rows r*16.., cols wv*16..
      va = MFMA16(xf[ks], bB[ks], va);   // V: same rows/cols
    }
    kacc[r] = ka;
#pragma unroll
    for (int rg = 0; rg < 4; ++rg)
      V_lds[wv * 16 + l15][r * 16 + 4 * l4 + rg] = f2bf(va[rg] + bvv);
  }
  __syncthreads();  // barrier B: all x reads complete (V also fully written)
#pragma unroll
  for (int r = 0; r < 16; ++r)
#pragma unroll
    for (int rg = 0; rg < 4; ++rg)
      KX[r * 16 + 4 * l4 + rg][wv * 16 + l15] = f2bf(kacc[r][rg] + bkv);
  __syncthreads();  // barrier C: K complete (old barrier 2)

  {  // in-block vmean over V^T rows
    int d = tid >> 2, seg = tid & 3;
    const u16* vr = &V_lds[d][seg * 64];
    float s = 0.f;
#pragma unroll
    for (int j = 0; j < 8; ++j) {
      uint4 u = *(const uint4*)(vr + j * 8);
      s += bf2f((u16)(u.x & 0xffff)) + bf2f((u16)(u.x >> 16));
      s += bf2f((u16)(u.y & 0xffff)) + bf2f((u16)(u.y >> 16));
      s += bf2f((u16)(u.z & 0xffff)) + bf2f((u16)(u.z >> 16));
      s += bf2f((u16)(u.w & 0xffff)) + bf2f((u16)(u.w >> 16));
    }
    s += __shfl_xor(s, 1); s += __shfl_xor(s, 2);
    if (seg == 0) vmean_lds[d] = s * (1.f / 256.f);
  }
  float lsum[2][4]; f32x4 cacc[2][8];
#pragma unroll
  for (int g = 0; g < 2; ++g)
#pragma unroll
    for (int rg = 0; rg < 4; ++rg) lsum[g][rg] = 0.f;
#pragma unroll
  for (int g = 0; g < 2; ++g)
#pragma unroll
    for (int ct = 0; ct < 8; ++ct) cacc[g][ct] = f32x4{0.f, 0.f, 0.f, 0.f};
  __syncthreads();  // barrier 3: vmean ready; no more block syncs

  // ---- attention: fixed-max softmax, 32 rows/wave ----
  const int nkv = (wv >> 1) + 1;
  for (int kv = 0; kv < nkv; ++kv) {
    const int s0 = kv * 64;
    f32x4 sacc[2][4];
#pragma unroll
    for (int g = 0; g < 2; ++g)
#pragma unroll
      for (int ct = 0; ct < 4; ++ct) sacc[g][ct] = f32x4{0.f, 0.f, 0.f, 0.f};
#pragma unroll
    for (int ct = 0; ct < 4; ++ct)
#pragma unroll
      for (int ks = 0; ks < 4; ++ks) {
        bf16x8 bfr = *(const bf16x8*)&KX[s0 + ct * 16 + l15][ks * 32 + l4 * 8];
#pragma unroll
        for (int g = 0; g < 2; ++g) sacc[g][ct] = MFMA16(qa[g][ks], bfr, sacc[g][ct]);
      }
    int km[4];
#pragma unroll
    for (int ct = 0; ct < 4; ++ct) km[ct] = mrow[s0 + ct * 16 + l15];
    float p[2][4][4];
#pragma unroll
    for (int g = 0; g < 2; ++g)
#pragma unroll
      for (int ct = 0; ct < 4; ++ct) {
        const int ss = s0 + ct * 16 + l15;
#pragma unroll
        for (int rg = 0; rg < 4; ++rg) {
          float sv = sacc[g][ct][rg] + rel_lds[ttg[g][rg] - ss + 255];
          bool msk = (ss > ttg[g][rg]) | (km[ct] == 0) | (qm[g][rg] == 0);
          sv = msk ? -1.0e9f : sv;
          float pv = __expf(sv);  // masked -> exactly 0
          p[g][ct][rg] = pv;
          lsum[g][rg] += pv;
        }
      }
#pragma unroll
    for (int c = 0; c < 2; ++c) {
#pragma unroll
      for (int g = 0; g < 2; ++g)
#pragma unroll
        for (int c2 = 0; c2 < 2; ++c2)
#pragma unroll
          for (int rg = 0; rg < 4; ++rg)
            P_lds[wv][g * 16 + 4 * l4 + rg][c2 * 16 + l15] = f2bf(p[g][2 * c + c2][rg]);
      bf16x8 pa[2];
#pragma unroll
      for (int g = 0; g < 2; ++g)
        pa[g] = *(const bf16x8*)&P_lds[wv][g * 16 + l15][l4 * 8];
#pragma unroll
      for (int ct = 0; ct < 8; ++ct) {
        bf16x8 vb = *(const bf16x8*)&V_lds[ct * 16 + l15][s0 + c * 32 + l4 * 8];
#pragma unroll
        for (int g = 0; g < 2; ++g) cacc[g][ct] = MFMA16(pa[g], vb, cacc[g][ct]);
      }
    }
  }
  float li[2][4];
#pragma unroll
  for (int g = 0; g < 2; ++g)
#pragma unroll
    for (int rg = 0; rg < 4; ++rg) {
      float rs = lsum[g][rg];
#pragma unroll
      for (int off = 1; off < 16; off <<= 1) rs += __shfl_xor(rs, off);
      li[g][rg] = rs;
    }
  // ---- ctx -> out-proj (ping-pong) -> residual+LN -> scatter ----
  bf16x8 ca[2][4];
#pragma unroll
  for (int q = 0; q < 4; ++q) {
#pragma unroll
    for (int g = 0; g < 2; ++g)
#pragma unroll
      for (int c2 = 0; c2 < 2; ++c2) {
        int ct = 2 * q + c2;
        float vm = vmean_lds[ct * 16 + l15];
#pragma unroll
        for (int rg = 0; rg < 4; ++rg) {
          float cval = cacc[g][ct][rg] / li[g][rg];
          cval = (qm[g][rg] == 0) ? vm : cval;
          P_lds[wv][g * 16 + 4 * l4 + rg][c2 * 16 + l15] = f2bf(cval);
        }
      }
#pragma unroll
    for (int g = 0; g < 2; ++g)
      ca[g][q] = *(const bf16x8*)&P_lds[wv][g * 16 + l15][l4 * 8];
  }
  f32x4 oacc[2][8];
#define OACC(CT)                                                           \
  do {                                                                     \
    oacc[0][CT] = t0; oacc[1][CT] = t1;                                    \
  } while (0)
#define MF8C(buf)                                                          \
  do {                                                                     \
    t0 = f32x4{0.f, 0.f, 0.f, 0.f}; t1 = f32x4{0.f, 0.f, 0.f, 0.f};       \
    _Pragma("unroll") for (int ks = 0; ks < 4; ++ks) {                     \
      t0 = MFMA16(ca[0][ks], buf[ks], t0);                                 \
      t1 = MFMA16(ca[1][ks], buf[ks], t1);                                 \
    }                                                                      \
  } while (0)
  LOADW4(bA, 384 + 0);
  LOADW4(bB, 384 + 16);
  MF8C(bA); LOADW4(bA, 384 + 2 * 16); OACC(0);
  MF8C(bB); LOADW4(bB, 384 + 3 * 16); OACC(1);
  MF8C(bA); LOADW4(bA, 384 + 4 * 16); OACC(2);
  MF8C(bB); LOADW4(bB, 384 + 5 * 16); OACC(3);
  MF8C(bA); LOADW4(bA, 384 + 6 * 16); OACC(4);
  MF8C(bB); LOADW4(bB, 384 + 7 * 16); OACC(5);
  MF8C(bA);                           OACC(6);
  MF8C(bB);                           OACC(7);

  float bpv[8], gv[8], bt[8];
#pragma unroll
  for (int ct = 0; ct < 8; ++ct) {
    int d = ct * 16 + l15;
    bpv[ct] = bp[d]; gv[ct] = ln_g[d]; bt[ct] = ln_b[d];
  }
#pragma unroll
  for (int g = 0; g < 2; ++g)
#pragma unroll
    for (int rg = 0; rg < 4; ++rg) {
      const int tg = ttg[g][rg];
      float yv[8], sum = 0.f, sq = 0.f;
#pragma unroll
      for (int ct = 0; ct < 8; ++ct) {
        uint32_t pr = xres[g][rg][ct >> 1];
        u16 xh = (ct & 1) ? (u16)(pr >> 16) : (u16)(pr & 0xffff);
        float v = oacc[g][ct][rg] + bpv[ct] + bf2f(xh);
        yv[ct] = v; sum += v; sq += v * v;
      }
#pragma unroll
      for (int off = 1; off < 16; off <<= 1) { sum += __shfl_xor(sum, off); sq += __shfl_xor(sq, off); }
      float mean = sum * (1.f / 128.f);
      float var = sq * (1.f / 128.f) - mean * mean;
      float rstd = rsqrtf(var + 1e-5f);
      float* orow = out + (((size_t)(bb * 256 + tg)) * 100 + rr) * 128;
#pragma unroll
      for (int ct = 0; ct < 8; ++ct)
        orow[ct * 16 + l15] = (yv[ct] - mean) * rstd * gv[ct] + bt[ct];
    }
#undef LOADW4
#undef MF8
#undef MF8C
#undef QSTORE
#undef OACC
}

extern "C" void kernel_launch(void* const* d_in, const int* in_sizes, int n_in,
                              void* d_out, int out_size, void* d_ws, size_t ws_size,
                              hipStream_t stream) {
  const float* x    = (const float*)d_in[0];
  const int*   mask = (const int*)d_in[1];
  const float* Wq   = (const float*)d_in[2];
  const float* bq   = (const float*)d_in[3];
  const float* Wk   = (const float*)d_in[4];
  const float* bk   = (const float*)d_in[5];
  const float* Wv   = (const float*)d_in[6];
  const float* bv   = (const float*)d_in[7];
  const float* Wp   = (const float*)d_in[8];
  const float* bp   = (const float*)d_in[9];
  const float* ln_g = (const float*)d_in[10];
  const float* ln_b = (const float*)d_in[11];
  const float* rel  = (const float*)d_in[12];
  float* out = (float*)d_out;
  u16* Wt = (u16*)d_ws;  // [4][128][128] bf16 transposed — only workspace use

  hipLaunchKernelGGL(prep_weights_kernel, dim3(4, 64), dim3(256), 0, stream, Wq, Wk, Wv, Wp, Wt);
  hipLaunchKernelGGL(fused10_kernel, dim3(400), dim3(512), 0, stream,
                     Wt, x, mask, rel, bq, bk, bv, bp, ln_g, ln_b, out);
}

// Round 25
// 74.746 us; speedup vs baseline: 1.1927x; 1.1212x over previous
//
#include <hip/hip_runtime.h>
#include <hip/hip_bf16.h>
#include <stdint.h>

typedef float f32x4 __attribute__((ext_vector_type(4)));
typedef __bf16 bf16x8 __attribute__((ext_vector_type(8)));
typedef unsigned short u16;

#define MFMA16(a, b, c) __builtin_amdgcn_mfma_f32_16x16x32_bf16((a), (b), (c), 0, 0, 0)

__device__ __forceinline__ u16 f2bf(float f) {
  union { float f; uint32_t u; } v; v.f = f;
  uint32_t u = v.u;
  return (u16)((u + 0x7fffu + ((u >> 16) & 1u)) >> 16);
}
__device__ __forceinline__ float bf2f(u16 h) {
  union { uint32_t u; float f; } v; v.u = ((uint32_t)h) << 16;
  return v.f;
}

// ---------------- kernel 0: weights -> bf16 transposed [c][k] -----------------
__global__ void prep_weights_kernel(const float* __restrict__ Wq, const float* __restrict__ Wk,
                                    const float* __restrict__ Wv, const float* __restrict__ Wp,
                                    u16* __restrict__ Wt) {
  int w = blockIdx.x;
  const float* W = (w == 0) ? Wq : (w == 1) ? Wk : (w == 2) ? Wv : Wp;
  int t = blockIdx.y * 256 + threadIdx.x;  // 0..16383
  int c = t >> 7, k = t & 127;
  Wt[(w * 128 + c) * 128 + k] = f2bf(W[k * 128 + c]);
}

// ---------------- FUSED kernel v13: fused10 + Wq STAGED IN LDS ---------------
// fused10 (83.4us champion) with the proven redundant-weight-elimination
// mechanism applied to the LAST untreated section: the Q GEMM. Wq (32KB) is
// staged ONCE per block into the then-dead V_lds region ([128][136] padded =
// same 2-way-conflict layout as KX); all 8 waves read Q's B-frags via
// ds_read_b128 instead of each loading all 16 global weight groups (8x L2
// redundancy removed). One extra BALANCED barrier (Q-done) before the K/V
// col-split overwrites V_lds. The freed bA/bB ping-pong registers let the K/V
// W-frag prefetch issue right after barrier A, flying under the whole Q
// section. All other structure identical to fused10 (per-element math
// unchanged: same fragments, same ks order).
__global__ __launch_bounds__(512, 2) void fused13_kernel(
    const u16* __restrict__ Wt, const float* __restrict__ x,
    const int* __restrict__ mask, const float* __restrict__ rel,
    const float* __restrict__ bq, const float* __restrict__ bk,
    const float* __restrict__ bv, const float* __restrict__ bp,
    const float* __restrict__ ln_g, const float* __restrict__ ln_b,
    float* __restrict__ out) {
  __shared__ u16 KX[256][136];        // x (per-wave) -> K               69632 B
  __shared__ u16 V_lds[128][264];     // Wq stage -> V^T [d][t]          67584 B
  __shared__ u16 P_lds[8][32][40];    // per-wave repack slices          20480 B
  __shared__ float rel_lds[511];      //                                  2044 B
  __shared__ float vmean_lds[128];    //                                   512 B -> 160252 B
  const int tid = threadIdx.x;
  const int n = blockIdx.x;
  const int bb = n / 100, rr = n - bb * 100;
  const int* mrow = mask + bb * 256;
  if (tid < 511) rel_lds[tid] = rel[tid];
  const int l = tid & 63, wv = tid >> 6, l15 = l & 15, l4 = l >> 4;
  const int tt0 = wv * 32;  // this wave's 32 q-rows

#define LOADW4(buf, ROWB)                                                  \
  do {                                                                     \
    const u16* _wp = Wt + (size_t)((ROWB) + l15) * 128 + l4 * 8;           \
    buf[0] = *(const bf16x8*)(_wp);                                        \
    buf[1] = *(const bf16x8*)(_wp + 32);                                   \
    buf[2] = *(const bf16x8*)(_wp + 64);                                   \
    buf[3] = *(const bf16x8*)(_wp + 96);                                   \
  } while (0)

  {  // cooperative Wq -> LDS (dead V_lds region, [128][136] padded layout)
    int row = tid >> 2, cb = (tid & 3) * 32;
    const u16* src = Wt + (size_t)row * 128 + cb;
    u16* dst = (u16*)V_lds + (size_t)row * 136 + cb;
#pragma unroll
    for (int j = 0; j < 4; ++j)
      *(bf16x8*)(dst + j * 8) = *(const bf16x8*)(src + j * 8);
  }
  {  // WAVE-PRIVATE stage, BATCHED: 16 loads issued together, then cvt+store
    int row = tt0 + (l >> 1), half = (l & 1) * 64;
    const float* src = x + ((size_t)(n * 256 + row)) * 128 + half;
    u16* dst = &KX[row][half];
    float4 xr[16];
#pragma unroll
    for (int j = 0; j < 16; ++j) xr[j] = ((const float4*)src)[j];
#pragma unroll
    for (int j = 0; j < 16; ++j) {
      dst[j * 4 + 0] = f2bf(xr[j].x); dst[j * 4 + 1] = f2bf(xr[j].y);
      dst[j * 4 + 2] = f2bf(xr[j].z); dst[j * 4 + 3] = f2bf(xr[j].w);
    }
  }
  int ttg[2][4], qm[2][4];
#pragma unroll
  for (int g = 0; g < 2; ++g)
#pragma unroll
    for (int rg = 0; rg < 4; ++rg) {
      ttg[g][rg] = tt0 + g * 16 + 4 * l4 + rg;
      qm[g][rg] = mrow[ttg[g][rg]];
    }

  // ---- per-wave reads of OWN x rows (A-frags + packed residual) ----
  bf16x8 af[2][4];
#pragma unroll
  for (int g = 0; g < 2; ++g)
#pragma unroll
    for (int ks = 0; ks < 4; ++ks)
      af[g][ks] = *(const bf16x8*)&KX[tt0 + g * 16 + l15][ks * 32 + l4 * 8];
  uint32_t xres[2][4][4];  // x[ttg[g][rg]][ct*16+l15], ct=2c|2c+1 packed
#pragma unroll
  for (int g = 0; g < 2; ++g)
#pragma unroll
    for (int rg = 0; rg < 4; ++rg) {
      const u16* xr = &KX[tt0 + g * 16 + 4 * l4 + rg][0];
#pragma unroll
      for (int c = 0; c < 4; ++c)
        xres[g][rg][c] = (uint32_t)xr[c * 32 + l15] | ((uint32_t)xr[c * 32 + 16 + l15] << 16);
    }
  __syncthreads();  // barrier A: x + Wq staged by ALL waves

  // K/V W-frag prefetch (own cols) — issued now, flies under the whole Q section
  bf16x8 bA[4], bB[4];
  LOADW4(bA, 128 + wv * 16);  // K W-frags
  LOADW4(bB, 256 + wv * 16);  // V W-frags

  const float scale = 0.088388347648318447f;  // 1/sqrt(128)
  f32x4 t0, t1;  // transient per-ct accumulators
#define MF8(buf)                                                           \
  do {                                                                     \
    t0 = f32x4{0.f, 0.f, 0.f, 0.f}; t1 = f32x4{0.f, 0.f, 0.f, 0.f};       \
    _Pragma("unroll") for (int ks = 0; ks < 4; ++ks) {                     \
      t0 = MFMA16(af[0][ks], buf[ks], t0);                                 \
      t1 = MFMA16(af[1][ks], buf[ks], t1);                                 \
    }                                                                      \
  } while (0)

  // ---- Q = x @ Wq + bq, B-frags from LDS (wq staged in V_lds region) ----
  bf16x8 qa[2][4];
  const u16* wq = (const u16*)V_lds;
#define QSTORE(CT)                                                         \
  do {                                                                     \
    float bqv = bq[(CT) * 16 + l15];                                       \
    _Pragma("unroll") for (int rg = 0; rg < 4; ++rg) {                     \
      P_lds[wv][4 * l4 + rg][((CT) & 1) * 16 + l15] = f2bf((t0[rg] + bqv) * scale); \
      P_lds[wv][16 + 4 * l4 + rg][((CT) & 1) * 16 + l15] = f2bf((t1[rg] + bqv) * scale); \
    }                                                                      \
    if ((CT) & 1) {                                                        \
      qa[0][(CT) >> 1] = *(const bf16x8*)&P_lds[wv][l15][l4 * 8];          \
      qa[1][(CT) >> 1] = *(const bf16x8*)&P_lds[wv][16 + l15][l4 * 8];     \
    }                                                                      \
  } while (0)
#define QSTEP(CT)                                                          \
  do {                                                                     \
    bf16x8 wqf[4];                                                         \
    _Pragma("unroll") for (int ks = 0; ks < 4; ++ks)                       \
      wqf[ks] = *(const bf16x8*)(wq + (size_t)((CT) * 16 + l15) * 136 + ks * 32 + l4 * 8); \
    MF8(wqf);                                                              \
    QSTORE(CT);                                                            \
  } while (0)
  QSTEP(0); QSTEP(1); QSTEP(2); QSTEP(3);
  QSTEP(4); QSTEP(5); QSTEP(6); QSTEP(7);
  __syncthreads();  // barrier Q: all waves done reading wq_lds (balanced work)

  // ---- K & V col-split: wave owns cols [wv*16, wv*16+16); W-frags resident --
  const float bkv = bk[wv * 16 + l15];
  const float bvv = bv[wv * 16 + l15];
  f32x4 kacc[16];
#pragma unroll
  for (int r = 0; r < 16; ++r) {
    bf16x8 xf[4];
#pragma unroll
    for (int ks = 0; ks < 4; ++ks)
      xf[ks] = *(const bf16x8*)&KX[r * 16 + l15][ks * 32 + l4 * 8];
    f32x4 ka = f32x4{0.f, 0.f, 0.f, 0.f};
    f32x4 va = f32x4{0.f, 0.f, 0.f, 0.f};
#pragma unroll
    for (int ks = 0; ks < 4; ++ks) {
      ka = MFMA16(xf[ks], bA[ks], ka);   // K: rows r*16.., cols wv*16..
      va = MFMA16(xf[ks], bB[ks], va);   // V: same rows/cols
    }
    kacc[r] = ka;
#pragma unroll
    for (int rg = 0; rg < 4; ++rg)
      V_lds[wv * 16 + l15][r * 16 + 4 * l4 + rg] = f2bf(va[rg] + bvv);
  }
  __syncthreads();  // barrier B: all x reads complete (V also fully written)
#pragma unroll
  for (int r = 0; r < 16; ++r)
#pragma unroll
    for (int rg = 0; rg < 4; ++rg)
      KX[r * 16 + 4 * l4 + rg][wv * 16 + l15] = f2bf(kacc[r][rg] + bkv);
  __syncthreads();  // barrier C: K complete

  {  // in-block vmean over V^T rows
    int d = tid >> 2, seg = tid & 3;
    const u16* vr = &V_lds[d][seg * 64];
    float s = 0.f;
#pragma unroll
    for (int j = 0; j < 8; ++j) {
      uint4 u = *(const uint4*)(vr + j * 8);
      s += bf2f((u16)(u.x & 0xffff)) + bf2f((u16)(u.x >> 16));
      s += bf2f((u16)(u.y & 0xffff)) + bf2f((u16)(u.y >> 16));
      s += bf2f((u16)(u.z & 0xffff)) + bf2f((u16)(u.z >> 16));
      s += bf2f((u16)(u.w & 0xffff)) + bf2f((u16)(u.w >> 16));
    }
    s += __shfl_xor(s, 1); s += __shfl_xor(s, 2);
    if (seg == 0) vmean_lds[d] = s * (1.f / 256.f);
  }
  float lsum[2][4]; f32x4 cacc[2][8];
#pragma unroll
  for (int g = 0; g < 2; ++g)
#pragma unroll
    for (int rg = 0; rg < 4; ++rg) lsum[g][rg] = 0.f;
#pragma unroll
  for (int g = 0; g < 2; ++g)
#pragma unroll
    for (int ct = 0; ct < 8; ++ct) cacc[g][ct] = f32x4{0.f, 0.f, 0.f, 0.f};
  __syncthreads();  // barrier 3: vmean ready; no more block syncs

  // ---- attention: fixed-max softmax, 32 rows/wave ----
  const int nkv = (wv >> 1) + 1;
  for (int kv = 0; kv < nkv; ++kv) {
    const int s0 = kv * 64;
    f32x4 sacc[2][4];
#pragma unroll
    for (int g = 0; g < 2; ++g)
#pragma unroll
      for (int ct = 0; ct < 4; ++ct) sacc[g][ct] = f32x4{0.f, 0.f, 0.f, 0.f};
#pragma unroll
    for (int ct = 0; ct < 4; ++ct)
#pragma unroll
      for (int ks = 0; ks < 4; ++ks) {
        bf16x8 bfr = *(const bf16x8*)&KX[s0 + ct * 16 + l15][ks * 32 + l4 * 8];
#pragma unroll
        for (int g = 0; g < 2; ++g) sacc[g][ct] = MFMA16(qa[g][ks], bfr, sacc[g][ct]);
      }
    int km[4];
#pragma unroll
    for (int ct = 0; ct < 4; ++ct) km[ct] = mrow[s0 + ct * 16 + l15];
    float p[2][4][4];
#pragma unroll
    for (int g = 0; g < 2; ++g)
#pragma unroll
      for (int ct = 0; ct < 4; ++ct) {
        const int ss = s0 + ct * 16 + l15;
#pragma unroll
        for (int rg = 0; rg < 4; ++rg) {
          float sv = sacc[g][ct][rg] + rel_lds[ttg[g][rg] - ss + 255];
          bool msk = (ss > ttg[g][rg]) | (km[ct] == 0) | (qm[g][rg] == 0);
          sv = msk ? -1.0e9f : sv;
          float pv = __expf(sv);  // masked -> exactly 0
          p[g][ct][rg] = pv;
          lsum[g][rg] += pv;
        }
      }
#pragma unroll
    for (int c = 0; c < 2; ++c) {
#pragma unroll
      for (int g = 0; g < 2; ++g)
#pragma unroll
        for (int c2 = 0; c2 < 2; ++c2)
#pragma unroll
          for (int rg = 0; rg < 4; ++rg)
            P_lds[wv][g * 16 + 4 * l4 + rg][c2 * 16 + l15] = f2bf(p[g][2 * c + c2][rg]);
      bf16x8 pa[2];
#pragma unroll
      for (int g = 0; g < 2; ++g)
        pa[g] = *(const bf16x8*)&P_lds[wv][g * 16 + l15][l4 * 8];
#pragma unroll
      for (int ct = 0; ct < 8; ++ct) {
        bf16x8 vb = *(const bf16x8*)&V_lds[ct * 16 + l15][s0 + c * 32 + l4 * 8];
#pragma unroll
        for (int g = 0; g < 2; ++g) cacc[g][ct] = MFMA16(pa[g], vb, cacc[g][ct]);
      }
    }
  }
  float li[2][4];
#pragma unroll
  for (int g = 0; g < 2; ++g)
#pragma unroll
    for (int rg = 0; rg < 4; ++rg) {
      float rs = lsum[g][rg];
#pragma unroll
      for (int off = 1; off < 16; off <<= 1) rs += __shfl_xor(rs, off);
      li[g][rg] = rs;
    }
  // ---- ctx -> out-proj (ping-pong) -> residual+LN -> scatter ----
  bf16x8 ca[2][4];
#pragma unroll
  for (int q = 0; q < 4; ++q) {
#pragma unroll
    for (int g = 0; g < 2; ++g)
#pragma unroll
      for (int c2 = 0; c2 < 2; ++c2) {
        int ct = 2 * q + c2;
        float vm = vmean_lds[ct * 16 + l15];
#pragma unroll
        for (int rg = 0; rg < 4; ++rg) {
          float cval = cacc[g][ct][rg] / li[g][rg];
          cval = (qm[g][rg] == 0) ? vm : cval;
          P_lds[wv][g * 16 + 4 * l4 + rg][c2 * 16 + l15] = f2bf(cval);
        }
      }
#pragma unroll
    for (int g = 0; g < 2; ++g)
      ca[g][q] = *(const bf16x8*)&P_lds[wv][g * 16 + l15][l4 * 8];
  }
  f32x4 oacc[2][8];
#define OACC(CT)                                                           \
  do {                                                                     \
    oacc[0][CT] = t0; oacc[1][CT] = t1;                                    \
  } while (0)
#define MF8C(buf)                                                          \
  do {                                                                     \
    t0 = f32x4{0.f, 0.f, 0.f, 0.f}; t1 = f32x4{0.f, 0.f, 0.f, 0.f};       \
    _Pragma("unroll") for (int ks = 0; ks < 4; ++ks) {                     \
      t0 = MFMA16(ca[0][ks], buf[ks], t0);                                 \
      t1 = MFMA16(ca[1][ks], buf[ks], t1);                                 \
    }                                                                      \
  } while (0)
  LOADW4(bA, 384 + 0);
  LOADW4(bB, 384 + 16);
  MF8C(bA); LOADW4(bA, 384 + 2 * 16); OACC(0);
  MF8C(bB); LOADW4(bB, 384 + 3 * 16); OACC(1);
  MF8C(bA); LOADW4(bA, 384 + 4 * 16); OACC(2);
  MF8C(bB); LOADW4(bB, 384 + 5 * 16); OACC(3);
  MF8C(bA); LOADW4(bA, 384 + 6 * 16); OACC(4);
  MF8C(bB); LOADW4(bB, 384 + 7 * 16); OACC(5);
  MF8C(bA);                           OACC(6);
  MF8C(bB);                           OACC(7);

  float bpv[8], gv[8], bt[8];
#pragma unroll
  for (int ct = 0; ct < 8; ++ct) {
    int d = ct * 16 + l15;
    bpv[ct] = bp[d]; gv[ct] = ln_g[d]; bt[ct] = ln_b[d];
  }
#pragma unroll
  for (int g = 0; g < 2; ++g)
#pragma unroll
    for (int rg = 0; rg < 4; ++rg) {
      const int tg = ttg[g][rg];
      float yv[8], sum = 0.f, sq = 0.f;
#pragma unroll
      for (int ct = 0; ct < 8; ++ct) {
        uint32_t pr = xres[g][rg][ct >> 1];
        u16 xh = (ct & 1) ? (u16)(pr >> 16) : (u16)(pr & 0xffff);
        float v = oacc[g][ct][rg] + bpv[ct] + bf2f(xh);
        yv[ct] = v; sum += v; sq += v * v;
      }
#pragma unroll
      for (int off = 1; off < 16; off <<= 1) { sum += __shfl_xor(sum, off); sq += __shfl_xor(sq, off); }
      float mean = sum * (1.f / 128.f);
      float var = sq * (1.f / 128.f) - mean * mean;
      float rstd = rsqrtf(var + 1e-5f);
      float* orow = out + (((size_t)(bb * 256 + tg)) * 100 + rr) * 128;
#pragma unroll
      for (int ct = 0; ct < 8; ++ct)
        orow[ct * 16 + l15] = (yv[ct] - mean) * rstd * gv[ct] + bt[ct];
    }
#undef LOADW4
#undef MF8
#undef MF8C
#undef QSTORE
#undef QSTEP
#undef OACC
}

extern "C" void kernel_launch(void* const* d_in, const int* in_sizes, int n_in,
                              void* d_out, int out_size, void* d_ws, size_t ws_size,
                              hipStream_t stream) {
  const float* x    = (const float*)d_in[0];
  const int*   mask = (const int*)d_in[1];
  const float* Wq   = (const float*)d_in[2];
  const float* bq   = (const float*)d_in[3];
  const float* Wk   = (const float*)d_in[4];
  const float* bk   = (const float*)d_in[5];
  const float* Wv   = (const float*)d_in[6];
  const float* bv   = (const float*)d_in[7];
  const float* Wp   = (const float*)d_in[8];
  const float* bp   = (const float*)d_in[9];
  const float* ln_g = (const float*)d_in[10];
  const float* ln_b = (const float*)d_in[11];
  const float* rel  = (const float*)d_in[12];
  float* out = (float*)d_out;
  u16* Wt = (u16*)d_ws;  // [4][128][128] bf16 transposed — only workspace use

  hipLaunchKernelGGL(prep_weights_kernel, dim3(4, 64), dim3(256), 0, stream, Wq, Wk, Wv, Wp, Wt);
  hipLaunchKernelGGL(fused13_kernel, dim3(400), dim3(512), 0, stream,
                     Wt, x, mask, rel, bq, bk, bv, bp, ln_g, ln_b, out);
}